// Round 7
// baseline (91.072 us; speedup 1.0000x reference)
//
#include <hip/hip_runtime.h>
#include <math.h>

// NormalLoss: for each template vertex (M=6890), take the K=15 scan points
// (N=20000) with LARGEST distance, among them pick the min-angle normal
// match, loss = mean ||sv[sel]-tv||.
//
// Round-7 design (round-6 ledger pins ~33 us on main; cross-lane ops ride
// the LDS pipe at ~50-120 cyc dependent latency, so the per-insert 6-op
// chains were structural):
//  * main kernel: NO per-candidate insert events. Scan ballots survivors
//    (d2 >= thr, thr FIXED between drains) into a wave-private LDS buffer
//    via popcount-prefix append (no cross-iteration chains). On >=64
//    survivors (or at scan end), drain: bitonic-sort the 64-chunk
//    (21 stages) + bitonic-merge into the running sorted top-64 list
//    (8 stages), tighten thr once. ~83 dependent cross-lane steps total
//    vs ~260 before.
//  * tie semantics exact: strict total order (d2 desc, idx asc); >= thr
//    ballots keep boundary ties; thr is always the 15th of a superset.
//  * hist / scan_scatter / reduce unchanged (absmax 0.0 five rounds).

constexpr int K = 15;
constexpr int NBUCK = 256;
constexpr int WAVES = 4;     // waves (=vertices) per block in main kernel
constexpr int CAP = 128;     // survivor buffer per wave; drain at >= CAP-64

__device__ __forceinline__ int bucket_of(float k2) {
    int b = (int)(k2 * 8.0f);           // 0.125-wide buckets over |p|^2 in [0,32)
    b = b > (NBUCK - 1) ? (NBUCK - 1) : b;
    return (NBUCK - 1) - b;             // bucket 0 = largest |p|
}

__global__ __launch_bounds__(256) void hist_kernel(
    const float* __restrict__ sv, int* __restrict__ blkhist, int N)
{
    __shared__ int h[NBUCK];
    int t = threadIdx.x;
    h[t] = 0;
    __syncthreads();
    int i = blockIdx.x * 256 + t;
    if (i < N) {
        float x = sv[3*i], y = sv[3*i+1], z = sv[3*i+2];
        atomicAdd(&h[bucket_of(fmaf(x, x, fmaf(y, y, z*z)))], 1);
    }
    __syncthreads();
    blkhist[blockIdx.x * NBUCK + t] = h[t];   // full-row overwrite (poison-safe)
}

__global__ __launch_bounds__(256) void scan_scatter_kernel(
    const float* __restrict__ sv,
    const int*   __restrict__ blkhist,  // [nblk][NBUCK]
    float4*      __restrict__ sorted,   // [N] out: (x,y,z,bitcast(origIdx))
    float*       __restrict__ smax,     // [nb] out: |p| upper bound at pos >= j*64
    int N, int nb, int nblk)
{
    __shared__ int tmp[NBUCK];
    __shared__ int startSh[NBUCK];
    __shared__ int cursor[NBUCK];
    const int t   = threadIdx.x;
    const int blk = blockIdx.x;

    int mine = 0, total = 0;
#pragma unroll 8
    for (int b = 0; b < nblk; ++b) {
        int v = blkhist[b * NBUCK + t];
        if (b < blk) mine += v;
        total += v;
    }
    tmp[t] = total;
    __syncthreads();
    for (int d = 1; d < NBUCK; d <<= 1) {
        int u = (t >= d) ? tmp[t - d] : 0;
        __syncthreads();
        tmp[t] += u;
        __syncthreads();
    }
    int startv = tmp[t] - total;        // exclusive bucket start
    startSh[t] = startv;
    cursor[t]  = startv + mine;         // this block's write base per bucket
    __syncthreads();

    if (blk == 0) {
        // smax[j]: bucket-edge upper bound on |p| for positions >= j*64;
        // exact and independent of within-bucket order.
        for (int j = t; j < nb; j += 256) {
            int pos = j * 64;
            int lo = 0, hi = NBUCK - 1;
            while (lo < hi) {
                int mid = (lo + hi + 1) >> 1;
                if (startSh[mid] <= pos) lo = mid; else hi = mid - 1;
            }
            int bOrig = (NBUCK - 1) - lo;
            smax[j] = sqrtf((float)(bOrig + 1) * 0.125f);
        }
    }

    int i = blk * 256 + t;
    if (i < N) {
        float x = sv[3*i], y = sv[3*i+1], z = sv[3*i+2];
        float k2 = fmaf(x, x, fmaf(y, y, z*z));
        int pos = atomicAdd(&cursor[bucket_of(k2)], 1);   // LDS atomic
        sorted[pos] = make_float4(x, y, z, __int_as_float(i));
    }
}

// 64-lane bitonic sort, descending by (v desc, idx asc) — strict total order
__device__ __forceinline__ void sort64(float& v, int& idx, int lane) {
#pragma unroll
    for (int k = 2; k <= 64; k <<= 1) {
#pragma unroll
        for (int j = k >> 1; j > 0; j >>= 1) {
            float ov = __shfl_xor(v, j);
            int   oi = __shfl_xor(idx, j);
            bool up    = ((lane & k) == 0);
            bool lower = ((lane & j) == 0);
            bool mine  = (v > ov) || (v == ov && idx < oi);
            bool keep  = lower ? (up ? mine : !mine) : (up ? !mine : mine);
            if (!keep) { v = ov; idx = oi; }
        }
    }
}

// merge sorted-desc B into sorted-desc A; A keeps the top-64 (sorted desc)
__device__ __forceinline__ void merge64(float& av, int& ai, float bv, int bi,
                                        int lane) {
    // reverse B -> A·B' is bitonic (desc then asc)
    bv = __shfl(bv, 63 - lane);
    bi = __shfl(bi, 63 - lane);
    // distance-64 stage is in-lane: keep the better element in A
    {
        bool aB = (av > bv) || (av == bv && ai < bi);
        av = aB ? av : bv;
        ai = aB ? ai : bi;
    }
    // clean the bitonic top half, descending
#pragma unroll
    for (int j = 32; j > 0; j >>= 1) {
        float ov = __shfl_xor(av, j);
        int   oi = __shfl_xor(ai, j);
        bool lower = ((lane & j) == 0);
        bool mine  = (av > ov) || (av == ov && ai < oi);
        bool keep  = lower ? mine : !mine;
        if (!keep) { av = ov; ai = oi; }
    }
}

template<bool SORTED>
__global__ __launch_bounds__(WAVES * 64) void knn_loss_kernel(
    const float4* __restrict__ pts,   // sorted points (SORTED only)
    const float*  __restrict__ smax,  // suffix |p| upper bound per 64-block
    const float*  __restrict__ sv,    // [N,3] original scan vertices
    const float*  __restrict__ tv,    // [M,3]
    const float*  __restrict__ sn,    // [N,3]
    const float*  __restrict__ tn,    // [M,3]
    float* __restrict__ partial,      // [gridDim.x] per-block sums
    int N, int M, float invM)
{
    __shared__ float sbD[WAVES][CAP];
    __shared__ int   sbI[WAVES][CAP];
    __shared__ float bsum[WAVES];
    const int lane = threadIdx.x & 63;
    const int w    = threadIdx.x >> 6;
    const int m    = blockIdx.x * WAVES + w;   // wave-uniform
    const bool valid = (m < M);                // wave-uniform branch

    float contrib = 0.0f;
    if (valid) {
        const float tvx = tv[3*m], tvy = tv[3*m+1], tvz = tv[3*m+2];
        const float tlen = sqrtf(tvx*tvx + tvy*tvy + tvz*tvz);
        float* bufD = sbD[w];
        int*   bufI = sbI[w];

        // ---- bootstrap: sort block 0 -> running top-64 list (av, ai) ----
        float av; int ai;
        {
            int l = (lane < N) ? lane : 0;
            float px, py, pz;
            if (SORTED) {
                float4 q = pts[l];
                px = q.x; py = q.y; pz = q.z; ai = __float_as_int(q.w);
            } else {
                px = sv[3*l]; py = sv[3*l+1]; pz = sv[3*l+2]; ai = l;
            }
            float dx = px - tvx, dy = py - tvy, dz = pz - tvz;
            av = fmaf(dx, dx, fmaf(dy, dy, dz * dz));
            if (lane >= N) { av = -1.0f; ai = 0x7FFFFFFF; }
        }
        sort64(av, ai, lane);
        float thr = __shfl(av, K - 1);   // 15th-largest d2 so far
        int cnt = 0;                     // wave-uniform survivor count

        // ---- scan: ballot-collect survivors; no per-event chains ----
        for (int ib = 64; ib < N; ib += 64) {
            int  i   = ib + lane;
            bool has = (i < N);
            float d2; int oi2;
            if (SORTED) {
                float4 q = pts[has ? i : 0];
                float bnd = smax[ib >> 6] + tlen;      // d <= |p| + |tv|
                if (bnd * bnd * 1.00001f < thr) break; // margin covers rounding
                float dx = q.x - tvx, dy = q.y - tvy, dz = q.z - tvz;
                d2 = fmaf(dx, dx, fmaf(dy, dy, dz * dz));
                oi2 = __float_as_int(q.w);
            } else {
                int g = has ? i : 0;
                float dx = sv[3*g] - tvx, dy = sv[3*g+1] - tvy, dz = sv[3*g+2] - tvz;
                d2 = fmaf(dx, dx, fmaf(dy, dy, dz * dz));
                oi2 = i;
            }
            bool cand = has && (d2 >= thr);   // >= keeps boundary ties
            unsigned long long msk = __ballot(cand);
            if (msk) {                        // wave-uniform
                int pos = cnt + __popcll(msk & ((1ull << lane) - 1ull));
                if (cand) { bufD[pos] = d2; bufI[pos] = oi2; }
                cnt += __popcll(msk);
                if (cnt >= CAP - 64) {        // drain (wave-uniform, bounded)
                    for (int b = 0; b < cnt; b += 64) {
                        int j = b + lane;
                        float bv = -1.0f; int bi2 = 0x7FFFFFFF;
                        if (j < cnt) { bv = bufD[j]; bi2 = bufI[j]; }
                        sort64(bv, bi2, lane);
                        merge64(av, ai, bv, bi2, lane);
                    }
                    cnt = 0;
                    thr = __shfl(av, K - 1);  // tighten once per drain
                }
            }
        }
        // final drain
        for (int b = 0; b < cnt; b += 64) {
            int j = b + lane;
            float bv = -1.0f; int bi2 = 0x7FFFFFFF;
            if (j < cnt) { bv = bufD[j]; bi2 = bufI[j]; }
            sort64(bv, bi2, lane);
            merge64(av, ai, bv, bi2, lane);
        }

        // ---- epilogue: argmin angle over top-K, tie-break by rank (= lane) ----
        const float tnx = tn[3*m], tny = tn[3*m+1], tnz = tn[3*m+2];
        float ang = 3.0e38f;
        int myI = ai;
        if (lane < K && myI != 0x7FFFFFFF) {
            float dot = sn[3*myI]*tnx + sn[3*myI+1]*tny + sn[3*myI+2]*tnz;
            dot = fminf(1.0f, fmaxf(-1.0f, dot));
            ang = acosf(dot) * 57.29577951308232f;   // degrees, matches jnp
        }
        float ba = ang; int br = lane; int bi = myI;
#pragma unroll
        for (int s = 1; s < 16; s <<= 1) {
            float oa  = __shfl_xor(ba, s);
            int   orr = __shfl_xor(br, s);
            int   oi  = __shfl_xor(bi, s);
            bool take = (oa < ba) || (oa == ba && orr < br);
            if (take) { ba = oa; br = orr; bi = oi; }
        }
        if (lane == 0) {
            float dx = sv[3*bi]   - tvx;
            float dy = sv[3*bi+1] - tvy;
            float dz = sv[3*bi+2] - tvz;
            contrib = sqrtf(dx*dx + dy*dy + dz*dz) * invM;
        }
    }

    if (lane == 0) bsum[w] = contrib;
    __syncthreads();
    if (threadIdx.x == 0)
        partial[blockIdx.x] = bsum[0] + bsum[1] + bsum[2] + bsum[3];
}

__global__ __launch_bounds__(256) void reduce_kernel(
    const float* __restrict__ partial, float* __restrict__ out, int n)
{
    __shared__ float sh[4];
    const int lane = threadIdx.x & 63;
    const int w    = threadIdx.x >> 6;
    float s = 0.0f;
    for (int i = threadIdx.x; i < n; i += 256) s += partial[i];
#pragma unroll
    for (int d = 1; d < 64; d <<= 1) s += __shfl_xor(s, d);
    if (lane == 0) sh[w] = s;
    __syncthreads();
    if (threadIdx.x == 0) out[0] = sh[0] + sh[1] + sh[2] + sh[3];
}

extern "C" void kernel_launch(void* const* d_in, const int* in_sizes, int n_in,
                              void* d_out, int out_size, void* d_ws, size_t ws_size,
                              hipStream_t stream) {
    const float* sv = (const float*)d_in[0];   // scan_vertices   [1,N,3]
    const float* tv = (const float*)d_in[1];   // template_vertices [1,M,3]
    const float* sn = (const float*)d_in[2];   // scan_normals    [N,3]
    const float* tn = (const float*)d_in[3];   // template_normals [M,3]
    // d_in[4] = K_knn (fixed 15, compile-time)

    int N = in_sizes[0] / 3;
    int M = in_sizes[1] / 3;
    int nb = (N + 63) / 64;
    float* out = (float*)d_out;
    float invM = 1.0f / (float)M;
    int grid  = (M + WAVES - 1) / WAVES;
    int nblk  = (N + 255) / 256;

    // d_ws layout: [sorted float4 x N][smax x nb][blkhist x nblk*256][partial x grid]
    size_t offSorted  = 0;
    size_t offSmax    = offSorted + (size_t)N * sizeof(float4);
    size_t offHist    = (offSmax + (size_t)nb * sizeof(float) + 15) & ~(size_t)15;
    size_t offPartial = offHist + (size_t)nblk * NBUCK * sizeof(int);
    size_t need       = offPartial + (size_t)grid * sizeof(float);

    if (ws_size >= need) {
        float4* sorted  = (float4*)((char*)d_ws + offSorted);
        float*  smax    = (float*) ((char*)d_ws + offSmax);
        int*    blkhist = (int*)   ((char*)d_ws + offHist);
        float*  partial = (float*) ((char*)d_ws + offPartial);

        hist_kernel        <<<nblk, 256, 0, stream>>>(sv, blkhist, N);
        scan_scatter_kernel<<<nblk, 256, 0, stream>>>(sv, blkhist, sorted,
                                                      smax, N, nb, nblk);
        knn_loss_kernel<true><<<grid, WAVES * 64, 0, stream>>>(
            sorted, smax, sv, tv, sn, tn, partial, N, M, invM);
        reduce_kernel      <<<1, 256, 0, stream>>>(partial, out, grid);
    } else if (ws_size >= (size_t)grid * sizeof(float)) {
        float* partial = (float*)d_ws;
        knn_loss_kernel<false><<<grid, WAVES * 64, 0, stream>>>(
            nullptr, nullptr, sv, tv, sn, tn, partial, N, M, invM);
        reduce_kernel      <<<1, 256, 0, stream>>>(partial, out, grid);
    }
}